// Round 12
// baseline (648.213 us; speedup 1.0000x reference)
//
#include <hip/hip_runtime.h>

typedef float f32x2 __attribute__((ext_vector_type(2)));
typedef float f32x4 __attribute__((ext_vector_type(4)));

#define BB 256
#define TT 1024
#define HH 128
#define CC 2
#define NR 2    // batch rows per block (grid = BB/NR)

// tanh(u) = 1 - 2/(exp(2u)+1); branchless. Validated R3-R10: absmax 9.77e-4.
__device__ __forceinline__ float ftanh(float u) {
    float e = __expf(2.0f * u);
    float r = __builtin_amdgcn_rcpf(e + 1.0f);
    return fmaf(-2.0f, r, 1.0f);
}

// broadcast lane j's value to all lanes via SGPR (VALU pipe, no LDS)
__device__ __forceinline__ float bcast(float v, int j) {
    return __int_as_float(__builtin_amdgcn_readlane(__float_as_int(v), j));
}

// v + cross-lane(v) via DPP: VALU pipe, no LDS.
#define DPP_ADD(v, ctrl)                                                     \
    ((v) + __int_as_float(__builtin_amdgcn_mov_dpp(                          \
         __float_as_int(v), (ctrl), 0xF, 0xF, true)))

// sum across 64 lanes, all-VALU (validated R10)
__device__ __forceinline__ float wave_sum(float q) {
    q = DPP_ADD(q, 0xB1);    // + xor1  (quad)
    q = DPP_ADD(q, 0x4E);    // + xor2  (quad)
    q = DPP_ADD(q, 0x124);   // + ror4  (row16)
    q = DPP_ADD(q, 0x128);   // + ror8  (row16) -> lane = its row16 sum
    return bcast(q, 0) + bcast(q, 16) + bcast(q, 32) + bcast(q, 48);
}

__global__ __launch_bounds__(256, 1) void rnn_kernel(
    const float* __restrict__ x, const float* __restrict__ W_ih,
    const float* __restrict__ W_hh, const float* __restrict__ b_ih,
    const float* __restrict__ b_hh, const float* __restrict__ W_fc,
    const float* __restrict__ b_fc, float* __restrict__ out)
{
    const int b   = blockIdx.x;         // 0..127
    const int tid = threadIdx.x;        // 0..255
    const int l   = tid & 63;
    const int wv  = tid >> 6;           // 0..3
    const int lq  = l & 31;
    const int kb  = wv << 5;            // this wave's k-quarter base
    const int rA  = l, rB = l + 64;     // partial rows this lane computes
    const int rF  = kb + lq;            // row this wave finalizes (dup lanes 32..63)

    __shared__ float xs[NR][TT + 8];    // input sequences (+pad)
    __shared__ float p2[2][NR][HH][4];  // [buf][row][h-row][src wave] partials
    __shared__ f32x2 qp[4][NR][4];      // [t&3][row][wave] logit partials

    // preload x rows (coalesced f32x4)
    #pragma unroll
    for (int r = 0; r < NR; ++r) {
        const f32x4* xr = (const f32x4*)(x + (size_t)(NR * b + r) * TT);
        ((f32x4*)xs[r])[tid] = xr[tid];
    }
    if (tid < 8) { xs[0][TT + tid] = 0.f; xs[1][TT + tid] = 0.f; }

    const float wih  = W_ih[rF];
    const float bias = b_ih[rF] + b_hh[rF];
    // halved: lanes 32..63 duplicate rows in wave_sum -> x2
    const float wf0  = 0.5f * W_fc[rF];
    const float wf1  = 0.5f * W_fc[HH + rF];
    const float bf0  = b_fc[0], bf1 = b_fc[1];

    // packed weights: wr[k] = {W_hh[rA][kb+k], W_hh[rB][kb+k]} -> 64 VGPRs
    f32x2 wr[32];
    {
        const f32x4* a4 = (const f32x4*)(W_hh + (size_t)rA * HH + kb);
        const f32x4* b4 = (const f32x4*)(W_hh + (size_t)rB * HH + kb);
        #pragma unroll
        for (int j = 0; j < 8; ++j) {
            f32x4 va = a4[j], vb = b4[j];
            wr[4*j+0] = f32x2{va.x, vb.x};
            wr[4*j+1] = f32x2{va.y, vb.y};
            wr[4*j+2] = f32x2{va.z, vb.z};
            wr[4*j+3] = f32x2{va.w, vb.w};
        }
    }

    float hn0 = 0.f, hn1 = 0.f;         // h_t[rF] for batch rows 0,1
    // out row base for lanes tid<NR (harmless for others)
    float* oo = out + (size_t)(NR * b + (tid & 1)) * TT * CC;

    __syncthreads();                    // xs visible
    float xc0 = xs[0][0], xc1 = xs[1][0];

    #pragma unroll 4
    for (int t = 0; t < TT; ++t) {
        const int buf = t & 1, qb = t & 3;

        // pin the weight pack live across iterations (in-loop: the allocator
        // cannot sink the loads back into the loop body)
        asm volatile("" : "+v"(wr[0]), "+v"(wr[1]), "+v"(wr[2]), "+v"(wr[3]),
                          "+v"(wr[4]), "+v"(wr[5]), "+v"(wr[6]), "+v"(wr[7]));
        asm volatile("" : "+v"(wr[8]), "+v"(wr[9]), "+v"(wr[10]), "+v"(wr[11]),
                          "+v"(wr[12]), "+v"(wr[13]), "+v"(wr[14]), "+v"(wr[15]));
        asm volatile("" : "+v"(wr[16]), "+v"(wr[17]), "+v"(wr[18]), "+v"(wr[19]),
                          "+v"(wr[20]), "+v"(wr[21]), "+v"(wr[22]), "+v"(wr[23]));
        asm volatile("" : "+v"(wr[24]), "+v"(wr[25]), "+v"(wr[26]), "+v"(wr[27]),
                          "+v"(wr[28]), "+v"(wr[29]), "+v"(wr[30]), "+v"(wr[31]));

        // ---- dual-row partial matvec over this wave's k-quarter (pk_fma).
        // lane k<32 holds h[kb+k] in hn -> bcast(hn,k) = h[kb+k].
        f32x2 a00 = {0.f,0.f}, a01 = {0.f,0.f};   // row 0
        f32x2 a10 = {0.f,0.f}, a11 = {0.f,0.f};   // row 1
        #pragma unroll
        for (int k = 0; k < 32; k += 2) {
            float s00 = bcast(hn0, k), s01 = bcast(hn0, k + 1);
            float s10 = bcast(hn1, k), s11 = bcast(hn1, k + 1);
            a00 = __builtin_elementwise_fma(wr[k],     f32x2{s00, s00}, a00);
            a10 = __builtin_elementwise_fma(wr[k],     f32x2{s10, s10}, a10);
            a01 = __builtin_elementwise_fma(wr[k + 1], f32x2{s01, s01}, a01);
            a11 = __builtin_elementwise_fma(wr[k + 1], f32x2{s11, s11}, a11);
        }
        f32x2 pr0 = a00 + a01, pr1 = a10 + a11;   // {rowA, rowB} partials

        // ship partials: [h-row][wave] layout -> post-barrier b128 gather is
        // conflict-free; these scatter writes are fire-and-forget pre-barrier
        p2[buf][0][rA][wv] = pr0.x;  p2[buf][0][rB][wv] = pr0.y;
        p2[buf][1][rA][wv] = pr1.x;  p2[buf][1][rB][wv] = pr1.y;

        // ---- logit partials of h_t (VALU-only DPP, validated R10)
        float q00 = wave_sum(wf0 * hn0), q01 = wave_sum(wf1 * hn0);
        float q10 = wave_sum(wf0 * hn1), q11 = wave_sum(wf1 * hn1);
        if (l == 0) {
            qp[qb][0][wv] = f32x2{q00, q01};
            qp[qb][1][wv] = f32x2{q10, q11};
        }

        // pre-barrier: u-bases and x prefetch
        const float base0 = fmaf(xc0, wih, bias);
        const float base1 = fmaf(xc1, wih, bias);
        xc0 = xs[0][t + 1];  xc1 = xs[1][t + 1];

        __syncthreads();                // the single per-step barrier

        // ---- out[t-1] = logits(h_t) for both rows (lanes 0,1)
        if (t > 0 && tid < NR) {
            f32x2 s = (qp[qb][tid][0] + qp[qb][tid][1])
                    + (qp[qb][tid][2] + qp[qb][tid][3]);
            s.x += bf0; s.y += bf1;
            *(f32x2*)(oo + (t - 1) * CC) = s;
        }

        // ---- combine: one conflict-free b128 per row (4 partials contiguous)
        f32x4 c0 = *(const f32x4*)&p2[buf][0][rF][0];
        f32x4 c1 = *(const f32x4*)&p2[buf][1][rF][0];
        hn0 = ftanh(base0 + ((c0.x + c0.y) + (c0.z + c0.w)));
        hn1 = ftanh(base1 + ((c1.x + c1.y) + (c1.z + c1.w)));
    }

    // epilogue: out[TT-1] = logits(h_TT) for both rows
    {
        float q00 = wave_sum(wf0 * hn0), q01 = wave_sum(wf1 * hn0);
        float q10 = wave_sum(wf0 * hn1), q11 = wave_sum(wf1 * hn1);
        if (l == 0) {
            qp[0][0][wv] = f32x2{q00, q01};
            qp[0][1][wv] = f32x2{q10, q11};
        }
    }
    __syncthreads();
    if (tid < NR) {
        f32x2 s = (qp[0][tid][0] + qp[0][tid][1])
                + (qp[0][tid][2] + qp[0][tid][3]);
        s.x += bf0; s.y += bf1;
        *(f32x2*)(oo + (TT - 1) * CC) = s;
    }
}

extern "C" void kernel_launch(void* const* d_in, const int* in_sizes, int n_in,
                              void* d_out, int out_size, void* d_ws, size_t ws_size,
                              hipStream_t stream) {
    const float* x    = (const float*)d_in[0];
    const float* W_ih = (const float*)d_in[1];
    const float* W_hh = (const float*)d_in[2];
    const float* b_ih = (const float*)d_in[3];
    const float* b_hh = (const float*)d_in[4];
    const float* W_fc = (const float*)d_in[5];
    const float* b_fc = (const float*)d_in[6];
    float* out = (float*)d_out;

    rnn_kernel<<<BB / NR, 256, 0, stream>>>(x, W_ih, W_hh, b_ih, b_hh, W_fc, b_fc, out);
}

// Round 13
// 540.615 us; speedup vs baseline: 1.1990x; 1.1990x over previous
//
#include <hip/hip_runtime.h>

typedef float f32x2 __attribute__((ext_vector_type(2)));
typedef float f32x4 __attribute__((ext_vector_type(4)));

#define BB 256
#define TT 1024
#define HH 128
#define CC 2
#define NG 2    // independent recurrence groups per block (4 waves each)

// tanh(u) = 1 - 2/(exp(2u)+1); branchless. Validated R3-R11: absmax 9.77e-4.
__device__ __forceinline__ float ftanh(float u) {
    float e = __expf(2.0f * u);
    float r = __builtin_amdgcn_rcpf(e + 1.0f);
    return fmaf(-2.0f, r, 1.0f);
}

// broadcast lane j's value to all lanes via SGPR (VALU pipe, no LDS)
__device__ __forceinline__ float bcast(float v, int j) {
    return __int_as_float(__builtin_amdgcn_readlane(__float_as_int(v), j));
}

// v + cross-lane(v) via DPP: VALU pipe, no LDS.
#define DPP_ADD(v, ctrl)                                                     \
    ((v) + __int_as_float(__builtin_amdgcn_mov_dpp(                          \
         __float_as_int(v), (ctrl), 0xF, 0xF, true)))

__global__ __launch_bounds__(512, 2) void rnn_kernel(
    const float* __restrict__ x, const float* __restrict__ W_ih,
    const float* __restrict__ W_hh, const float* __restrict__ b_ih,
    const float* __restrict__ b_hh, const float* __restrict__ W_fc,
    const float* __restrict__ b_fc, float* __restrict__ out)
{
    const int b   = blockIdx.x;         // 0..127
    const int tid = threadIdx.x;        // 0..511
    const int g   = tid >> 8;           // recurrence group 0/1 (indep. batch rows)
    const int t2  = tid & 255;          // index within group
    const int l   = tid & 63;
    const int wv  = (tid >> 6) & 3;     // wave within group
    const int lq  = l & 31;
    const int kb  = wv << 5;            // this wave's k-quarter base
    const int rA  = l, rB = l + 64;     // partial rows this lane computes
    const int rF  = kb + lq;            // row this wave finalizes (dup lanes 32..63)

    __shared__ float xs[NG][TT + 8];    // input sequences (+pad)
    __shared__ f32x2 p2[2][NG][4][64];  // [buf][group][src wave][lane] = {pA,pB}
    __shared__ f32x2 qp[4][NG][4];      // [t&3][group][wave] logit partials

    // preload x row for this group (256 lanes x f32x4, coalesced)
    {
        const f32x4* xr = (const f32x4*)(x + (size_t)(NG * b + g) * TT);
        ((f32x4*)xs[g])[t2] = xr[t2];
    }
    if (t2 < 8) xs[g][TT + t2] = 0.f;   // prefetch pad

    const float wih  = W_ih[rF];
    const float bias = b_ih[rF] + b_hh[rF];
    // split-class: lanes 0..31 carry class 0, lanes 32..63 (dup rows) class 1
    const float wfs  = (l < 32) ? W_fc[rF] : W_fc[HH + rF];
    const float bf0  = b_fc[0], bf1 = b_fc[1];

    // per-lane weights: rows rA,rB over k in [kb, kb+32) -> 64 floats
    // (reloaded from L1/L2 per step by the allocator; proven tolerable R9/R10)
    float wa[32], wb[32];
    {
        const f32x4* a4 = (const f32x4*)(W_hh + (size_t)rA * HH + kb);
        const f32x4* b4 = (const f32x4*)(W_hh + (size_t)rB * HH + kb);
        #pragma unroll
        for (int j = 0; j < 8; ++j) {
            f32x4 va = a4[j], vb = b4[j];
            wa[4*j+0] = va.x; wa[4*j+1] = va.y; wa[4*j+2] = va.z; wa[4*j+3] = va.w;
            wb[4*j+0] = vb.x; wb[4*j+1] = vb.y; wb[4*j+2] = vb.z; wb[4*j+3] = vb.w;
        }
    }

    float hn = 0.f;                     // h_t[rF] (lanes 32..63 duplicate 0..31)
    float* o = out + (size_t)(NG * b + g) * TT * CC;

    __syncthreads();                    // xs visible
    float xcur = xs[g][0];

    #pragma unroll 4
    for (int t = 0; t < TT; ++t) {
        const int buf = t & 1, qb = t & 3;

        // ---- partial matvec over this wave's k-quarter; h via readlane.
        // lane k (k<32) holds h[kb+k] in hn -> bcast(hn,k) = h[kb+k].
        float aA0 = 0.f, aA1 = 0.f, aB0 = 0.f, aB1 = 0.f;
        #pragma unroll
        for (int k = 0; k < 32; k += 2) {
            float s0 = bcast(hn, k);
            float s1 = bcast(hn, k + 1);
            aA0 = fmaf(wa[k],     s0, aA0);
            aB0 = fmaf(wb[k],     s0, aB0);
            aA1 = fmaf(wa[k + 1], s1, aA1);
            aB1 = fmaf(wb[k + 1], s1, aB1);
        }
        f32x2 pr = { aA0 + aA1, aB0 + aB1 };
        p2[buf][g][wv][l] = pr;         // b64 ship, 2-way alias = free

        // ---- logit partials of h_t: split-class DPP reduce (half of R10's ops)
        {
            float q = wfs * hn;
            q = DPP_ADD(q, 0xB1);       // + xor1 (quad)
            q = DPP_ADD(q, 0x4E);       // + xor2 (quad)
            q = DPP_ADD(q, 0x124);      // + ror4 (row16)
            q = DPP_ADD(q, 0x128);      // + ror8 (row16) -> lane = row16 sum
            float q0 = bcast(q, 0)  + bcast(q, 16);   // class 0 (lanes 0..31)
            float q1 = bcast(q, 32) + bcast(q, 48);   // class 1 (lanes 32..63)
            if (l == 0) qp[qb][g][wv] = f32x2{q0, q1};
        }

        // pre-barrier: u-base and x prefetch (off the post-barrier chain)
        const float base  = fmaf(xcur, wih, bias);
        const float xnext = xs[g][t + 1];

        __syncthreads();                // per-step barrier (aligns both groups;
                                        // indep. waves still fill each other's stalls)

        // ---- out[t-1] = logits(h_t): qp[t&3] written THIS iteration pre-barrier
        if (t > 0 && t2 == 0) {
            f32x2 s = (qp[qb][g][0] + qp[qb][g][1]) + (qp[qb][g][2] + qp[qb][g][3]);
            s.x += bf0; s.y += bf1;
            *(f32x2*)(o + (t - 1) * CC) = s;
        }

        // ---- combine the 4 k-quarter partials of row rF (R10-proven pattern)
        const float* pf = (const float*)&p2[buf][g][0][0]
                        + ((((wv & 1) << 5) + lq) << 1) + (wv >> 1);
        float p0 = pf[0], p1 = pf[128], pv2 = pf[256], pv3 = pf[384];
        hn = ftanh(base + ((p0 + p1) + (pv2 + pv3)));
        xcur = xnext;
    }

    // epilogue: out[TT-1] = logits(h_TT)
    {
        float q = wfs * hn;
        q = DPP_ADD(q, 0xB1);
        q = DPP_ADD(q, 0x4E);
        q = DPP_ADD(q, 0x124);
        q = DPP_ADD(q, 0x128);
        float q0 = bcast(q, 0)  + bcast(q, 16);
        float q1 = bcast(q, 32) + bcast(q, 48);
        if (l == 0) qp[0][g][wv] = f32x2{q0, q1};
    }
    __syncthreads();
    if (t2 == 0) {
        f32x2 s = (qp[0][g][0] + qp[0][g][1]) + (qp[0][g][2] + qp[0][g][3]);
        s.x += bf0; s.y += bf1;
        *(f32x2*)(o + (TT - 1) * CC) = s;
    }
}

extern "C" void kernel_launch(void* const* d_in, const int* in_sizes, int n_in,
                              void* d_out, int out_size, void* d_ws, size_t ws_size,
                              hipStream_t stream) {
    const float* x    = (const float*)d_in[0];
    const float* W_ih = (const float*)d_in[1];
    const float* W_hh = (const float*)d_in[2];
    const float* b_ih = (const float*)d_in[3];
    const float* b_hh = (const float*)d_in[4];
    const float* W_fc = (const float*)d_in[5];
    const float* b_fc = (const float*)d_in[6];
    float* out = (float*)d_out;

    rnn_kernel<<<BB / NG, 512, 0, stream>>>(x, W_ih, W_hh, b_ih, b_hh, W_fc, b_fc, out);
}